// Round 2
// baseline (12098.565 us; speedup 1.0000x reference)
//
#include <hip/hip_runtime.h>

#define N_NODES 100000
#define NLAYERS 4
#define NPROP 2
#define NGRAPHS 50
#define NE_MAIN 400000
#define NE_SET 300000

// ---------------- static device scratch (avoids any ws_size dependence) ----------------
__device__ __align__(16) float g_x[(size_t)N_NODES * 256];
__device__ __align__(16) float g_pi[(size_t)N_NODES * 256];
__device__ __align__(16) float g_agg[(size_t)N_NODES * 288];
__device__ __align__(16) float g_dinv[9 * N_NODES];   // [0]=main, [1..4]=inner, [5..8]=fwd
__device__ __align__(16) float g_pooled[NGRAPHS * 256];
__device__ int g_cnt[4];
__device__ int g_lists[NLAYERS * N_NODES];

// ----------------------------- setup kernels -----------------------------

__global__ __launch_bounds__(256) void k_init() {
    int i = blockIdx.x * blockDim.x + threadIdx.x;
    if (i < 9 * N_NODES) g_dinv[i] = 1.0f;
    if (i < NGRAPHS * 256) g_pooled[i] = 0.f;
    if (i < 4) g_cnt[i] = 0;
}

__global__ __launch_bounds__(256) void k_count_deg(const int* __restrict__ dst, int ne,
                                                   int slot) {
    int i = blockIdx.x * blockDim.x + threadIdx.x;
    if (i < ne) atomicAdd(&g_dinv[(size_t)slot * N_NODES + dst[i]], 1.0f);
}

__global__ __launch_bounds__(256) void k_rsqrt() {
    int i = blockIdx.x * blockDim.x + threadIdx.x;
    if (i < 9 * N_NODES) g_dinv[i] = rsqrtf(g_dinv[i]);
}

__global__ __launch_bounds__(256) void k_lists(const int* __restrict__ layers) {
    int i = blockIdx.x * blockDim.x + threadIdx.x;
    if (i >= N_NODES) return;
    int l = layers[i];
    int p = atomicAdd(&g_cnt[l], 1);
    g_lists[l * N_NODES + p] = i;
}

// ----------------------------- conv0 (K=16) -----------------------------

__global__ __launch_bounds__(256) void k_agginit16(const float* __restrict__ xin) {
    int t = blockIdx.x * blockDim.x + threadIdx.x;  // over N*16
    if (t >= N_NODES * 16) return;
    float dv = g_dinv[t >> 4];
    g_agg[t] = dv * dv * xin[t];
}

__global__ __launch_bounds__(256) void k_aggedge16(const float* __restrict__ xin,
                                                   const int* __restrict__ es,
                                                   const int* __restrict__ ed) {
    int t = blockIdx.x * blockDim.x + threadIdx.x;  // over NE_MAIN*16
    if (t >= NE_MAIN * 16) return;
    int e = t >> 4, k = t & 15;
    int s = es[e], d = ed[e];
    float nrm = g_dinv[s] * g_dinv[d];
    atomicAdd(&g_agg[d * 16 + k], nrm * xin[s * 16 + k]);
}

__global__ __launch_bounds__(256) void k_gemm0(const float* __restrict__ W,
                                               const float* __restrict__ bias) {
    __shared__ float a[128];
    int base = blockIdx.x * 8;
    int t = threadIdx.x;
    if (t < 128) a[t] = g_agg[base * 16 + t];
    __syncthreads();
    float bb = bias[t];
    for (int r = 0; r < 8; r++) {
        float acc = bb;
#pragma unroll
        for (int k = 0; k < 16; k++) acc += a[r * 16 + k] * W[k * 256 + t];
        g_x[(size_t)(base + r) * 256 + t] = acc;
    }
}

// ----------------------------- 288-dim aggregation -----------------------------

// wave-per-row self-loop init: agg[i] = (1/deg_i) * [x_i | static_i]
__global__ __launch_bounds__(256) void k_agginit(const float* __restrict__ fs,
                                                 int slot, int layer) {
    int w = (blockIdx.x * blockDim.x + threadIdx.x) >> 6;
    int lane = threadIdx.x & 63;
    int count = (layer >= 0) ? g_cnt[layer] : N_NODES;
    if (w >= count) return;
    int i = (layer >= 0) ? g_lists[layer * N_NODES + w] : w;
    float dv = g_dinv[(size_t)slot * N_NODES + i];
    float d2 = dv * dv;
    const float* xr = g_x + (size_t)i * 256;
    float* ar = g_agg + (size_t)i * 288;
    float4 v = *(const float4*)(xr + lane * 4);
    v.x *= d2; v.y *= d2; v.z *= d2; v.w *= d2;
    *(float4*)(ar + lane * 4) = v;
    if (lane < 8) {
        float4 s = *(const float4*)(fs + (size_t)i * 32 + lane * 4);
        s.x *= d2; s.y *= d2; s.z *= d2; s.w *= d2;
        *(float4*)(ar + 256 + lane * 4) = s;
    }
}

// wave-per-edge scatter: agg[dst] += norm * [x_src | static_src], only if layers[dst]==mask
__global__ __launch_bounds__(256) void k_aggedge(const float* __restrict__ fs,
                                                 const int* __restrict__ es,
                                                 const int* __restrict__ ed,
                                                 const int* __restrict__ layers,
                                                 int mask, int slot) {
    int w = (blockIdx.x * blockDim.x + threadIdx.x) >> 6;
    int lane = threadIdx.x & 63;
    if (w >= NE_SET) return;
    int d = ed[w];
    if (mask >= 0 && layers[d] != mask) return;
    int s = es[w];
    float nrm = g_dinv[(size_t)slot * N_NODES + s] * g_dinv[(size_t)slot * N_NODES + d];
    float4 v = *(const float4*)(g_x + (size_t)s * 256 + lane * 4);
    float* ap = g_agg + (size_t)d * 288 + lane * 4;
    atomicAdd(ap + 0, nrm * v.x);
    atomicAdd(ap + 1, nrm * v.y);
    atomicAdd(ap + 2, nrm * v.z);
    atomicAdd(ap + 3, nrm * v.w);
    if (lane < 32) {
        atomicAdd(g_agg + (size_t)d * 288 + 256 + lane, nrm * fs[(size_t)s * 32 + lane]);
    }
}

// ----------------------------- main GEMM (K=288, N=256, masked rows) -----------------------------
// block: 64 rows x 256 cols, threads 16x16, each thread 4 rows x 16 cols

__global__ __launch_bounds__(256) void k_gemm288(const float* __restrict__ W,
                                                 const float* __restrict__ bias,
                                                 int layer, int topi) {
    int count = (layer >= 0) ? g_cnt[layer] : N_NODES;
    int base = blockIdx.x * 64;
    if (base >= count) return;
    float* out = topi ? g_pi : g_x;
    __shared__ float aT[32 * 68];   // aT[k*68 + r]
    __shared__ float Wt[32 * 256];  // Wt[k*256 + c]
    __shared__ int rows[64];
    int t = threadIdx.x;
    if (t < 64) {
        int r = base + t;
        rows[t] = (r < count) ? ((layer >= 0) ? g_lists[layer * N_NODES + r] : r) : -1;
    }
    __syncthreads();
    int tr = t >> 4, tc = t & 15;
    float acc[4][16];
#pragma unroll
    for (int r = 0; r < 4; r++)
#pragma unroll
        for (int j = 0; j < 16; j++) acc[r][j] = 0.f;

    for (int k0 = 0; k0 < 288; k0 += 32) {
#pragma unroll
        for (int li = 0; li < 2; li++) {
            int idx = li * 256 + t;    // 512 float4 loads cover 64r x 32k
            int r = idx >> 3;
            int k4 = idx & 7;
            int row = rows[r];
            float4 v;
            if (row >= 0) v = *(const float4*)&g_agg[(size_t)row * 288 + k0 + k4 * 4];
            else { v.x = v.y = v.z = v.w = 0.f; }
            aT[(k4 * 4 + 0) * 68 + r] = v.x;
            aT[(k4 * 4 + 1) * 68 + r] = v.y;
            aT[(k4 * 4 + 2) * 68 + r] = v.z;
            aT[(k4 * 4 + 3) * 68 + r] = v.w;
        }
#pragma unroll
        for (int li = 0; li < 8; li++) {
            int idx = li * 256 + t;    // 2048 float4 loads cover 32k x 256c
            int k = idx >> 6;
            int c4 = idx & 63;
            *(float4*)&Wt[k * 256 + c4 * 4] = *(const float4*)&W[(size_t)(k0 + k) * 256 + c4 * 4];
        }
        __syncthreads();
        for (int k = 0; k < 32; k++) {
            float4 a4 = *(const float4*)&aT[k * 68 + tr * 4];
            float a[4] = {a4.x, a4.y, a4.z, a4.w};
            float b[16];
            *(float4*)&b[0]  = *(const float4*)&Wt[k * 256 + tc * 16];
            *(float4*)&b[4]  = *(const float4*)&Wt[k * 256 + tc * 16 + 4];
            *(float4*)&b[8]  = *(const float4*)&Wt[k * 256 + tc * 16 + 8];
            *(float4*)&b[12] = *(const float4*)&Wt[k * 256 + tc * 16 + 12];
#pragma unroll
            for (int r = 0; r < 4; r++)
#pragma unroll
                for (int j = 0; j < 16; j++) acc[r][j] += a[r] * b[j];
        }
        __syncthreads();
    }
#pragma unroll
    for (int r = 0; r < 4; r++) {
        int row = rows[tr * 4 + r];
        if (row < 0) continue;
        float* op = out + (size_t)row * 256 + tc * 16;
#pragma unroll
        for (int j = 0; j < 16; j++) op[j] = acc[r][j] + bias[tc * 16 + j];
    }
}

// ----------------------------- misc -----------------------------

__global__ __launch_bounds__(256) void k_copy_rows(int layer) {
    int w = (blockIdx.x * blockDim.x + threadIdx.x) >> 6;
    int lane = threadIdx.x & 63;
    if (w >= g_cnt[layer]) return;
    int i = g_lists[layer * N_NODES + w];
    *(float4*)(g_x + (size_t)i * 256 + lane * 4) =
        *(const float4*)(g_pi + (size_t)i * 256 + lane * 4);
}

__global__ __launch_bounds__(256) void k_relu() {
    int i = blockIdx.x * blockDim.x + threadIdx.x;
    if (i >= N_NODES * 64) return;
    float4 v = ((float4*)g_x)[i];
    v.x = fmaxf(v.x, 0.f); v.y = fmaxf(v.y, 0.f);
    v.z = fmaxf(v.z, 0.f); v.w = fmaxf(v.w, 0.f);
    ((float4*)g_x)[i] = v;
}

__global__ __launch_bounds__(256) void k_pool(const int* __restrict__ batch) {
    __shared__ int bs[128];
    int i0 = blockIdx.x * 128;
    if (threadIdx.x < 128) {
        int i = i0 + threadIdx.x;
        bs[threadIdx.x] = (i < N_NODES) ? batch[i] : -1;
    }
    __syncthreads();
    int c = threadIdx.x;
    int lim = min(128, N_NODES - i0);
    float acc = 0.f;
    int cur = bs[0];
    for (int ii = 0; ii < lim; ii++) {
        int g = bs[ii];
        if (g != cur) { atomicAdd(&g_pooled[cur * 256 + c], acc); acc = 0.f; cur = g; }
        acc += g_x[(size_t)(i0 + ii) * 256 + c];
    }
    atomicAdd(&g_pooled[cur * 256 + c], acc);
}

__global__ void k_final(const float* __restrict__ W_lin, const float* __restrict__ b_lin,
                        float* __restrict__ out) {
    int g = blockIdx.x;
    int lane = threadIdx.x;  // 64
    float4 p = *(const float4*)(g_pooled + g * 256 + lane * 4);
    float4 w = *(const float4*)(W_lin + lane * 4);
    float s = p.x * w.x + p.y * w.y + p.z * w.z + p.w * w.w;
    for (int o = 32; o > 0; o >>= 1) s += __shfl_down(s, o);
    if (lane == 0) out[g] = s + b_lin[0];
}

// ----------------------------- host -----------------------------

extern "C" void kernel_launch(void* const* d_in, const int* in_sizes, int n_in,
                              void* d_out, int out_size, void* d_ws, size_t ws_size,
                              hipStream_t stream) {
    const float* xin   = (const float*)d_in[0];
    const float* fs    = (const float*)d_in[1];
    const int* ei      = (const int*)d_in[2];
    const int* inner   = (const int*)d_in[3];
    const int* fwd     = (const int*)d_in[4];
    const int* layers  = (const int*)d_in[6];
    const int* batch   = (const int*)d_in[7];
    const float* W_up  = (const float*)d_in[8];
    const float* b_up  = (const float*)d_in[9];
    const float* W_in  = (const float*)d_in[10];
    const float* b_in  = (const float*)d_in[11];
    const float* W_fw  = (const float*)d_in[12];
    const float* b_fw  = (const float*)d_in[13];
    const float* W_lin = (const float*)d_in[14];
    const float* b_lin = (const float*)d_in[15];
    float* out = (float*)d_out;

    // --- init + degrees -> dinv for the 9 live edge sets ---
    k_init<<<(9 * N_NODES + 255) / 256, 256, 0, stream>>>();
    k_count_deg<<<(NE_MAIN + 255) / 256, 256, 0, stream>>>(ei + NE_MAIN, NE_MAIN, 0);
    for (int il = 0; il < NLAYERS; il++) {
        k_count_deg<<<(NE_SET + 255) / 256, 256, 0, stream>>>(
            inner + il * 2 * NE_SET + NE_SET, NE_SET, 1 + il);
        k_count_deg<<<(NE_SET + 255) / 256, 256, 0, stream>>>(
            fwd + il * 2 * NE_SET + NE_SET, NE_SET, 5 + il);
    }
    k_rsqrt<<<(9 * N_NODES + 255) / 256, 256, 0, stream>>>();
    k_lists<<<(N_NODES + 255) / 256, 256, 0, stream>>>(layers);

    // --- conv0: x = gcn(xin, edge_index) @ W_up + b_up ---
    k_agginit16<<<(N_NODES * 16 + 255) / 256, 256, 0, stream>>>(xin);
    k_aggedge16<<<(NE_MAIN * 16 + 255) / 256, 256, 0, stream>>>(xin, ei, ei + NE_MAIN);
    k_gemm0<<<N_NODES / 8, 256, 0, stream>>>(W_up, b_up);

    auto conv = [&](const int* es, const int* ed, int slot, int mask,
                    const float* W, const float* bias, int layer, int topi) {
        k_agginit<<<25000, 256, 0, stream>>>(fs, slot, layer);
        k_aggedge<<<NE_SET / 4, 256, 0, stream>>>(fs, es, ed, layers, mask, slot);
        k_gemm288<<<(N_NODES + 63) / 64, 256, 0, stream>>>(W, bias, layer, topi);
    };

    for (int p = 0; p < NPROP; p++) {
        // forward sweep
        for (int il = 0; il < NLAYERS; il++) {
            const int* es = inner + il * 2 * NE_SET;
            const int* ed = es + NE_SET;
            if (il < NLAYERS - 1) {
                conv(es, ed, 1 + il, il, W_in, b_in, il, 0);
                const int* fes = fwd + il * 2 * NE_SET;
                const int* fed = fes + NE_SET;
                conv(fes, fed, 5 + il, il + 1, W_fw, b_fw, il + 1, 0);
            } else {
                // full conv -> partial_inner (needed later), then masked copy into x
                conv(es, ed, 1 + il, -1, W_in, b_in, -1, 1);
                k_copy_rows<<<25000, 256, 0, stream>>>(3);
            }
        }
        k_relu<<<(N_NODES * 64 + 255) / 256, 256, 0, stream>>>();
        // backward sweep (conv on inner_edges; backward_edges conv is dead code)
        for (int il = NLAYERS - 1; il >= 0; il--) {
            if (il >= 1) k_copy_rows<<<25000, 256, 0, stream>>>(il - 1);
            const int* es = inner + il * 2 * NE_SET;
            const int* ed = es + NE_SET;
            conv(es, ed, 1 + il, il, W_in, b_in, il, 0);
        }
        k_relu<<<(N_NODES * 64 + 255) / 256, 256, 0, stream>>>();
    }

    // --- pooling + final linear ---
    k_pool<<<(N_NODES + 127) / 128, 256, 0, stream>>>(batch);
    k_final<<<NGRAPHS, 64, 0, stream>>>(W_lin, b_lin, out);
}

// Round 3
// 4523.714 us; speedup vs baseline: 2.6745x; 2.6745x over previous
//
#include <hip/hip_runtime.h>

#define N_NODES 100000
#define NLAYERS 4
#define NPROP 2
#define NGRAPHS 50
#define NE_MAIN 400000
#define NE_SET 300000
#define NSETS 9            // 0=main, 1..4=inner, 5..8=fwd
#define CSR_TOTAL (NE_MAIN + 8 * NE_SET)

// ---------------- static device scratch ----------------
__device__ __align__(16) float g_x[(size_t)N_NODES * 256];
__device__ __align__(16) float g_pi[(size_t)N_NODES * 256];
__device__ __align__(16) float g_agg[(size_t)N_NODES * 288];
__device__ __align__(16) float g_dinv[NSETS * N_NODES];
__device__ __align__(16) float g_pooled[NGRAPHS * 256];
__device__ int g_deg[NSETS * N_NODES];
__device__ int g_cur[NSETS * N_NODES];
__device__ int g_off[NSETS * (N_NODES + 1)];
__device__ int g_csr_src[CSR_TOTAL];
__device__ float g_csr_nrm[CSR_TOTAL];
__device__ int g_cnt[4];
__device__ int g_lists[NLAYERS * N_NODES];

__host__ __device__ inline int csr_base(int slot) {
    return slot == 0 ? 0 : NE_MAIN + (slot - 1) * NE_SET;
}

// ----------------------------- setup -----------------------------

__global__ __launch_bounds__(256) void k_init() {
    int i = blockIdx.x * blockDim.x + threadIdx.x;
    if (i < NSETS * N_NODES) { g_deg[i] = 0; g_cur[i] = 0; }
    if (i < NGRAPHS * 256) g_pooled[i] = 0.f;
    if (i < 4) g_cnt[i] = 0;
}

__global__ __launch_bounds__(256) void k_count_deg(const int* __restrict__ dst, int ne,
                                                   int slot) {
    int i = blockIdx.x * blockDim.x + threadIdx.x;
    if (i < ne) atomicAdd(&g_deg[slot * N_NODES + dst[i]], 1);
}

__global__ __launch_bounds__(256) void k_dinv() {
    int i = blockIdx.x * blockDim.x + threadIdx.x;
    if (i < NSETS * N_NODES) g_dinv[i] = rsqrtf(1.0f + (float)g_deg[i]);
}

#define SCAN_T 1024
#define SCAN_SEQ 8
__global__ __launch_bounds__(SCAN_T) void k_scan() {  // one block per set
    int set = blockIdx.x;
    const int* deg = g_deg + (size_t)set * N_NODES;
    int* off = g_off + (size_t)set * (N_NODES + 1);
    __shared__ int sm[SCAN_T];
    __shared__ int s_carry;
    int t = threadIdx.x;
    if (t == 0) s_carry = 0;
    __syncthreads();
    for (int base = 0; base < N_NODES; base += SCAN_T * SCAN_SEQ) {
        int v[SCAN_SEQ];
        int sum = 0;
        int idx0 = base + t * SCAN_SEQ;
#pragma unroll
        for (int j = 0; j < SCAN_SEQ; j++) {
            int id = idx0 + j;
            v[j] = (id < N_NODES) ? deg[id] : 0;
            sum += v[j];
        }
        sm[t] = sum;
        __syncthreads();
        for (int o = 1; o < SCAN_T; o <<= 1) {
            int u = (t >= o) ? sm[t - o] : 0;
            __syncthreads();
            sm[t] += u;
            __syncthreads();
        }
        int total = sm[SCAN_T - 1];
        int run = s_carry + sm[t] - sum;  // exclusive prefix for this thread's chunk
#pragma unroll
        for (int j = 0; j < SCAN_SEQ; j++) {
            int id = idx0 + j;
            if (id < N_NODES) off[id] = run;
            run += v[j];
        }
        __syncthreads();
        if (t == 0) s_carry += total;
        __syncthreads();
    }
    if (t == 0) off[N_NODES] = s_carry;
}

__global__ __launch_bounds__(256) void k_fill_csr(const int* __restrict__ es,
                                                  const int* __restrict__ ed,
                                                  int ne, int slot) {
    int e = blockIdx.x * blockDim.x + threadIdx.x;
    if (e >= ne) return;
    int s = es[e], d = ed[e];
    int pos = atomicAdd(&g_cur[slot * N_NODES + d], 1);
    int b = csr_base(slot) + g_off[slot * (N_NODES + 1) + d] + pos;
    g_csr_src[b] = s;
    g_csr_nrm[b] = g_dinv[slot * N_NODES + s] * g_dinv[slot * N_NODES + d];
}

__global__ __launch_bounds__(256) void k_lists(const int* __restrict__ layers) {
    int i = blockIdx.x * blockDim.x + threadIdx.x;
    if (i >= N_NODES) return;
    int l = layers[i];
    int p = atomicAdd(&g_cnt[l], 1);
    g_lists[l * N_NODES + p] = i;
}

// ----------------------------- conv0 (K=16) -----------------------------

__global__ __launch_bounds__(256) void k_gather16(const float* __restrict__ xin) {
    int g = blockIdx.x * blockDim.x + threadIdx.x;
    int i = g >> 4, lane = g & 15;  // 16 lanes per node
    if (i >= N_NODES) return;
    float dv = g_dinv[i];
    float acc = dv * dv * xin[i * 16 + lane];
    int e0 = g_off[i], e1 = g_off[i + 1];
    for (int e = e0; e < e1; e++) {
        int s = g_csr_src[e];
        float nrm = g_csr_nrm[e];
        acc += nrm * xin[s * 16 + lane];
    }
    g_agg[i * 16 + lane] = acc;
}

__global__ __launch_bounds__(256) void k_gemm0(const float* __restrict__ W,
                                               const float* __restrict__ bias) {
    __shared__ float a[128];
    int base = blockIdx.x * 8;
    int t = threadIdx.x;
    if (t < 128) a[t] = g_agg[base * 16 + t];
    __syncthreads();
    float bb = bias[t];
    for (int r = 0; r < 8; r++) {
        float acc = bb;
#pragma unroll
        for (int k = 0; k < 16; k++) acc += a[r * 16 + k] * W[k * 256 + t];
        g_x[(size_t)(base + r) * 256 + t] = acc;
    }
}

// ----------------------------- 288-dim gather (self-loop fused, no atomics) ----------

__global__ __launch_bounds__(256) void k_gather(const float* __restrict__ fs,
                                                int slot, int layer) {
    int w = (blockIdx.x * blockDim.x + threadIdx.x) >> 6;
    int lane = threadIdx.x & 63;
    int count = (layer >= 0) ? g_cnt[layer] : N_NODES;
    if (w >= count) return;
    int i = (layer >= 0) ? g_lists[layer * N_NODES + w] : w;
    float dv = g_dinv[(size_t)slot * N_NODES + i];
    float d2 = dv * dv;
    // self loop
    float4 acc = *(const float4*)&g_x[(size_t)i * 256 + lane * 4];
    acc.x *= d2; acc.y *= d2; acc.z *= d2; acc.w *= d2;
    float4 accs = {0.f, 0.f, 0.f, 0.f};
    if (lane < 8) {
        accs = *(const float4*)&fs[(size_t)i * 32 + lane * 4];
        accs.x *= d2; accs.y *= d2; accs.z *= d2; accs.w *= d2;
    }
    const int* offp = g_off + (size_t)slot * (N_NODES + 1);
    int e0 = offp[i] + csr_base(slot);
    int e1 = offp[i + 1] + csr_base(slot);
    for (int e = e0; e < e1; e++) {
        int s = g_csr_src[e];
        float nrm = g_csr_nrm[e];
        float4 v = *(const float4*)&g_x[(size_t)s * 256 + lane * 4];
        acc.x += nrm * v.x; acc.y += nrm * v.y;
        acc.z += nrm * v.z; acc.w += nrm * v.w;
        if (lane < 8) {
            float4 sv = *(const float4*)&fs[(size_t)s * 32 + lane * 4];
            accs.x += nrm * sv.x; accs.y += nrm * sv.y;
            accs.z += nrm * sv.z; accs.w += nrm * sv.w;
        }
    }
    float* ar = g_agg + (size_t)i * 288;
    *(float4*)(ar + lane * 4) = acc;
    if (lane < 8) *(float4*)(ar + 256 + lane * 4) = accs;
}

// ----------------------------- main GEMM (K=288, N=256, masked rows) -----------------

__global__ __launch_bounds__(256) void k_gemm288(const float* __restrict__ W,
                                                 const float* __restrict__ bias,
                                                 int layer, int topi) {
    int count = (layer >= 0) ? g_cnt[layer] : N_NODES;
    int base = blockIdx.x * 64;
    if (base >= count) return;
    float* out = topi ? g_pi : g_x;
    __shared__ float aT[32 * 68];
    __shared__ float Wt[32 * 256];
    __shared__ int rows[64];
    int t = threadIdx.x;
    if (t < 64) {
        int r = base + t;
        rows[t] = (r < count) ? ((layer >= 0) ? g_lists[layer * N_NODES + r] : r) : -1;
    }
    __syncthreads();
    int tr = t >> 4, tc = t & 15;
    float acc[4][16];
#pragma unroll
    for (int r = 0; r < 4; r++)
#pragma unroll
        for (int j = 0; j < 16; j++) acc[r][j] = 0.f;

    for (int k0 = 0; k0 < 288; k0 += 32) {
#pragma unroll
        for (int li = 0; li < 2; li++) {
            int idx = li * 256 + t;
            int r = idx >> 3;
            int k4 = idx & 7;
            int row = rows[r];
            float4 v;
            if (row >= 0) v = *(const float4*)&g_agg[(size_t)row * 288 + k0 + k4 * 4];
            else { v.x = v.y = v.z = v.w = 0.f; }
            aT[(k4 * 4 + 0) * 68 + r] = v.x;
            aT[(k4 * 4 + 1) * 68 + r] = v.y;
            aT[(k4 * 4 + 2) * 68 + r] = v.z;
            aT[(k4 * 4 + 3) * 68 + r] = v.w;
        }
#pragma unroll
        for (int li = 0; li < 8; li++) {
            int idx = li * 256 + t;
            int k = idx >> 6;
            int c4 = idx & 63;
            *(float4*)&Wt[k * 256 + c4 * 4] = *(const float4*)&W[(size_t)(k0 + k) * 256 + c4 * 4];
        }
        __syncthreads();
        for (int k = 0; k < 32; k++) {
            float4 a4 = *(const float4*)&aT[k * 68 + tr * 4];
            float a[4] = {a4.x, a4.y, a4.z, a4.w};
            float b[16];
            *(float4*)&b[0]  = *(const float4*)&Wt[k * 256 + tc * 16];
            *(float4*)&b[4]  = *(const float4*)&Wt[k * 256 + tc * 16 + 4];
            *(float4*)&b[8]  = *(const float4*)&Wt[k * 256 + tc * 16 + 8];
            *(float4*)&b[12] = *(const float4*)&Wt[k * 256 + tc * 16 + 12];
#pragma unroll
            for (int r = 0; r < 4; r++)
#pragma unroll
                for (int j = 0; j < 16; j++) acc[r][j] += a[r] * b[j];
        }
        __syncthreads();
    }
#pragma unroll
    for (int r = 0; r < 4; r++) {
        int row = rows[tr * 4 + r];
        if (row < 0) continue;
        float* op = out + (size_t)row * 256 + tc * 16;
#pragma unroll
        for (int j = 0; j < 16; j++) op[j] = acc[r][j] + bias[tc * 16 + j];
    }
}

// ----------------------------- misc -----------------------------

__global__ __launch_bounds__(256) void k_copy_rows(int layer) {
    int w = (blockIdx.x * blockDim.x + threadIdx.x) >> 6;
    int lane = threadIdx.x & 63;
    if (w >= g_cnt[layer]) return;
    int i = g_lists[layer * N_NODES + w];
    *(float4*)(g_x + (size_t)i * 256 + lane * 4) =
        *(const float4*)(g_pi + (size_t)i * 256 + lane * 4);
}

__global__ __launch_bounds__(256) void k_relu() {
    int i = blockIdx.x * blockDim.x + threadIdx.x;
    if (i >= N_NODES * 64) return;
    float4 v = ((float4*)g_x)[i];
    v.x = fmaxf(v.x, 0.f); v.y = fmaxf(v.y, 0.f);
    v.z = fmaxf(v.z, 0.f); v.w = fmaxf(v.w, 0.f);
    ((float4*)g_x)[i] = v;
}

__global__ __launch_bounds__(256) void k_pool(const int* __restrict__ batch) {
    __shared__ int bs[128];
    int i0 = blockIdx.x * 128;
    if (threadIdx.x < 128) {
        int i = i0 + threadIdx.x;
        bs[threadIdx.x] = (i < N_NODES) ? batch[i] : -1;
    }
    __syncthreads();
    int c = threadIdx.x;
    int lim = min(128, N_NODES - i0);
    float acc = 0.f;
    int cur = bs[0];
    for (int ii = 0; ii < lim; ii++) {
        int g = bs[ii];
        if (g != cur) { atomicAdd(&g_pooled[cur * 256 + c], acc); acc = 0.f; cur = g; }
        acc += g_x[(size_t)(i0 + ii) * 256 + c];
    }
    atomicAdd(&g_pooled[cur * 256 + c], acc);
}

__global__ void k_final(const float* __restrict__ W_lin, const float* __restrict__ b_lin,
                        float* __restrict__ out) {
    int g = blockIdx.x;
    int lane = threadIdx.x;  // 64
    float4 p = *(const float4*)(g_pooled + g * 256 + lane * 4);
    float4 w = *(const float4*)(W_lin + lane * 4);
    float s = p.x * w.x + p.y * w.y + p.z * w.z + p.w * w.w;
    for (int o = 32; o > 0; o >>= 1) s += __shfl_down(s, o);
    if (lane == 0) out[g] = s + b_lin[0];
}

// ----------------------------- host -----------------------------

extern "C" void kernel_launch(void* const* d_in, const int* in_sizes, int n_in,
                              void* d_out, int out_size, void* d_ws, size_t ws_size,
                              hipStream_t stream) {
    const float* xin   = (const float*)d_in[0];
    const float* fs    = (const float*)d_in[1];
    const int* ei      = (const int*)d_in[2];
    const int* inner   = (const int*)d_in[3];
    const int* fwd     = (const int*)d_in[4];
    const int* layers  = (const int*)d_in[6];
    const int* batch   = (const int*)d_in[7];
    const float* W_up  = (const float*)d_in[8];
    const float* b_up  = (const float*)d_in[9];
    const float* W_in  = (const float*)d_in[10];
    const float* b_in  = (const float*)d_in[11];
    const float* W_fw  = (const float*)d_in[12];
    const float* b_fw  = (const float*)d_in[13];
    const float* W_lin = (const float*)d_in[14];
    const float* b_lin = (const float*)d_in[15];
    float* out = (float*)d_out;

    // --- CSR build for the 9 live edge sets ---
    k_init<<<(NSETS * N_NODES + 255) / 256, 256, 0, stream>>>();
    k_count_deg<<<(NE_MAIN + 255) / 256, 256, 0, stream>>>(ei + NE_MAIN, NE_MAIN, 0);
    for (int il = 0; il < NLAYERS; il++) {
        k_count_deg<<<(NE_SET + 255) / 256, 256, 0, stream>>>(
            inner + il * 2 * NE_SET + NE_SET, NE_SET, 1 + il);
        k_count_deg<<<(NE_SET + 255) / 256, 256, 0, stream>>>(
            fwd + il * 2 * NE_SET + NE_SET, NE_SET, 5 + il);
    }
    k_dinv<<<(NSETS * N_NODES + 255) / 256, 256, 0, stream>>>();
    k_scan<<<NSETS, SCAN_T, 0, stream>>>();
    k_fill_csr<<<(NE_MAIN + 255) / 256, 256, 0, stream>>>(ei, ei + NE_MAIN, NE_MAIN, 0);
    for (int il = 0; il < NLAYERS; il++) {
        const int* ip = inner + il * 2 * NE_SET;
        const int* fp = fwd + il * 2 * NE_SET;
        k_fill_csr<<<(NE_SET + 255) / 256, 256, 0, stream>>>(ip, ip + NE_SET, NE_SET, 1 + il);
        k_fill_csr<<<(NE_SET + 255) / 256, 256, 0, stream>>>(fp, fp + NE_SET, NE_SET, 5 + il);
    }
    k_lists<<<(N_NODES + 255) / 256, 256, 0, stream>>>(layers);

    // --- conv0 ---
    k_gather16<<<(N_NODES * 16 + 255) / 256, 256, 0, stream>>>(xin);
    k_gemm0<<<N_NODES / 8, 256, 0, stream>>>(W_up, b_up);

    auto conv = [&](int slot, const float* W, const float* bias, int layer, int topi) {
        k_gather<<<25000, 256, 0, stream>>>(fs, slot, layer);
        k_gemm288<<<(N_NODES + 63) / 64, 256, 0, stream>>>(W, bias, layer, topi);
    };

    for (int p = 0; p < NPROP; p++) {
        for (int il = 0; il < NLAYERS; il++) {
            if (il < NLAYERS - 1) {
                conv(1 + il, W_in, b_in, il, 0);
                conv(5 + il, W_fw, b_fw, il + 1, 0);   // fwd conv (il=3 fwd is dead)
            } else {
                conv(1 + il, W_in, b_in, -1, 1);       // full -> partial_inner
                k_copy_rows<<<25000, 256, 0, stream>>>(3);
            }
        }
        k_relu<<<(N_NODES * 64 + 255) / 256, 256, 0, stream>>>();
        for (int il = NLAYERS - 1; il >= 0; il--) {
            if (il >= 1) k_copy_rows<<<25000, 256, 0, stream>>>(il - 1);
            conv(1 + il, W_in, b_in, il, 0);
        }
        k_relu<<<(N_NODES * 64 + 255) / 256, 256, 0, stream>>>();
    }

    k_pool<<<(N_NODES + 127) / 128, 256, 0, stream>>>(batch);
    k_final<<<NGRAPHS, 64, 0, stream>>>(W_lin, b_lin, out);
}

// Round 4
// 3954.198 us; speedup vs baseline: 3.0597x; 1.1440x over previous
//
#include <hip/hip_runtime.h>

#define N_NODES 100000
#define NLAYERS 4
#define NPROP 2
#define NGRAPHS 50
#define NE_MAIN 400000
#define NE_SET 300000
#define NSETS 9            // 0=main, 1..4=inner, 5..8=fwd
#define CSR_TOTAL (NE_MAIN + 8 * NE_SET)

// ---------------- static device scratch ----------------
__device__ __align__(16) float g_x[(size_t)N_NODES * 256];
__device__ __align__(16) float g_pi[(size_t)N_NODES * 256];
__device__ __align__(16) float g_agg[(size_t)N_NODES * 288];
__device__ __align__(16) float g_dinv[NSETS * N_NODES];
__device__ __align__(16) float g_pooled[NGRAPHS * 256];
__device__ int g_deg[NSETS * N_NODES];
__device__ int g_cur[NSETS * N_NODES];
__device__ int g_off[NSETS * (N_NODES + 1)];
__device__ int g_csr_src[CSR_TOTAL];
__device__ float g_csr_nrm[CSR_TOTAL];
__device__ int g_cnt[4];
__device__ int g_lists[NLAYERS * N_NODES];

__host__ __device__ inline int csr_base(int slot) {
    return slot == 0 ? 0 : NE_MAIN + (slot - 1) * NE_SET;
}

// decompose linear edge id over [main | inner0..3 | fwd0..3]
__device__ inline void edge_decode(int t, const int* ei, const int* inner, const int* fwd,
                                   int& slot, const int*& es, const int*& ed, int& e) {
    if (t < NE_MAIN) {
        slot = 0; e = t; es = ei; ed = ei + NE_MAIN;
    } else {
        int r = t - NE_MAIN;
        int grp = r / NE_SET;          // 0..7
        e = r - grp * NE_SET;
        slot = 1 + grp;                // 1..4 inner, 5..8 fwd
        const int* base = (grp < 4) ? (inner + grp * 2 * NE_SET)
                                    : (fwd + (grp - 4) * 2 * NE_SET);
        es = base; ed = base + NE_SET;
    }
}

// ----------------------------- setup -----------------------------

__global__ __launch_bounds__(256) void k_init() {
    int i = blockIdx.x * blockDim.x + threadIdx.x;
    if (i < NSETS * N_NODES) { g_deg[i] = 0; g_cur[i] = 0; }
    if (i < NGRAPHS * 256) g_pooled[i] = 0.f;
    if (i < 4) g_cnt[i] = 0;
}

__global__ __launch_bounds__(256) void k_count_all(const int* __restrict__ ei,
                                                   const int* __restrict__ inner,
                                                   const int* __restrict__ fwd) {
    int t = blockIdx.x * blockDim.x + threadIdx.x;
    if (t >= CSR_TOTAL) return;
    int slot, e; const int *es, *ed;
    edge_decode(t, ei, inner, fwd, slot, es, ed, e);
    atomicAdd(&g_deg[slot * N_NODES + ed[e]], 1);
}

__global__ __launch_bounds__(256) void k_dinv() {
    int i = blockIdx.x * blockDim.x + threadIdx.x;
    if (i < NSETS * N_NODES) g_dinv[i] = rsqrtf(1.0f + (float)g_deg[i]);
}

#define SCAN_T 1024
#define SCAN_SEQ 8
__global__ __launch_bounds__(SCAN_T) void k_scan() {  // one block per set
    int set = blockIdx.x;
    const int* deg = g_deg + (size_t)set * N_NODES;
    int* off = g_off + (size_t)set * (N_NODES + 1);
    __shared__ int sm[SCAN_T];
    __shared__ int s_carry;
    int t = threadIdx.x;
    if (t == 0) s_carry = 0;
    __syncthreads();
    for (int base = 0; base < N_NODES; base += SCAN_T * SCAN_SEQ) {
        int v[SCAN_SEQ];
        int sum = 0;
        int idx0 = base + t * SCAN_SEQ;
#pragma unroll
        for (int j = 0; j < SCAN_SEQ; j++) {
            int id = idx0 + j;
            v[j] = (id < N_NODES) ? deg[id] : 0;
            sum += v[j];
        }
        sm[t] = sum;
        __syncthreads();
        for (int o = 1; o < SCAN_T; o <<= 1) {
            int u = (t >= o) ? sm[t - o] : 0;
            __syncthreads();
            sm[t] += u;
            __syncthreads();
        }
        int total = sm[SCAN_T - 1];
        int run = s_carry + sm[t] - sum;
#pragma unroll
        for (int j = 0; j < SCAN_SEQ; j++) {
            int id = idx0 + j;
            if (id < N_NODES) off[id] = run;
            run += v[j];
        }
        __syncthreads();
        if (t == 0) s_carry += total;
        __syncthreads();
    }
    if (t == 0) off[N_NODES] = s_carry;
}

__global__ __launch_bounds__(256) void k_fill_all(const int* __restrict__ ei,
                                                  const int* __restrict__ inner,
                                                  const int* __restrict__ fwd) {
    int t = blockIdx.x * blockDim.x + threadIdx.x;
    if (t >= CSR_TOTAL) return;
    int slot, e; const int *es, *ed;
    edge_decode(t, ei, inner, fwd, slot, es, ed, e);
    int s = es[e], d = ed[e];
    int pos = atomicAdd(&g_cur[slot * N_NODES + d], 1);
    int b = csr_base(slot) + g_off[slot * (N_NODES + 1) + d] + pos;
    g_csr_src[b] = s;
    g_csr_nrm[b] = g_dinv[slot * N_NODES + s] * g_dinv[slot * N_NODES + d];
}

// block-local histogram -> 4 global atomics per block (order within layer is
// nondeterministic but all consumers are order-invariant per row)
__global__ __launch_bounds__(256) void k_lists(const int* __restrict__ layers) {
    __shared__ int lcnt[4];
    __shared__ int lbase[4];
    int i = blockIdx.x * blockDim.x + threadIdx.x;
    if (threadIdx.x < 4) lcnt[threadIdx.x] = 0;
    __syncthreads();
    int l = -1, p = 0;
    if (i < N_NODES) {
        l = layers[i];
        p = atomicAdd(&lcnt[l], 1);
    }
    __syncthreads();
    if (threadIdx.x < 4) lbase[threadIdx.x] = atomicAdd(&g_cnt[threadIdx.x], lcnt[threadIdx.x]);
    __syncthreads();
    if (l >= 0) g_lists[l * N_NODES + lbase[l] + p] = i;
}

// ----------------------------- conv0 (K=16) -----------------------------

__global__ __launch_bounds__(256) void k_gather16(const float* __restrict__ xin) {
    int g = blockIdx.x * blockDim.x + threadIdx.x;
    int i = g >> 4, lane = g & 15;
    if (i >= N_NODES) return;
    float dv = g_dinv[i];
    float acc = dv * dv * xin[i * 16 + lane];
    int e0 = g_off[i], e1 = g_off[i + 1];
    for (int e = e0; e < e1; e++) {
        int s = g_csr_src[e];
        float nrm = g_csr_nrm[e];
        acc += nrm * xin[s * 16 + lane];
    }
    g_agg[i * 16 + lane] = acc;
}

__global__ __launch_bounds__(256) void k_gemm0(const float* __restrict__ W,
                                               const float* __restrict__ bias) {
    __shared__ float a[128];
    int base = blockIdx.x * 8;
    int t = threadIdx.x;
    if (t < 128) a[t] = g_agg[base * 16 + t];
    __syncthreads();
    float bb = bias[t];
    for (int r = 0; r < 8; r++) {
        float acc = bb;
#pragma unroll
        for (int k = 0; k < 16; k++) acc += a[r * 16 + k] * W[k * 256 + t];
        g_x[(size_t)(base + r) * 256 + t] = acc;
    }
}

// ----------------------------- 288-dim gather (self-loop fused, no atomics) ----------

__global__ __launch_bounds__(256) void k_gather(const float* __restrict__ fs,
                                                int slot, int layer) {
    int w = (blockIdx.x * blockDim.x + threadIdx.x) >> 6;
    int lane = threadIdx.x & 63;
    int count = (layer >= 0) ? g_cnt[layer] : N_NODES;
    if (w >= count) return;
    int i = (layer >= 0) ? g_lists[layer * N_NODES + w] : w;
    float dv = g_dinv[(size_t)slot * N_NODES + i];
    float d2 = dv * dv;
    float4 acc = *(const float4*)&g_x[(size_t)i * 256 + lane * 4];
    acc.x *= d2; acc.y *= d2; acc.z *= d2; acc.w *= d2;
    float4 accs = {0.f, 0.f, 0.f, 0.f};
    if (lane < 8) {
        accs = *(const float4*)&fs[(size_t)i * 32 + lane * 4];
        accs.x *= d2; accs.y *= d2; accs.z *= d2; accs.w *= d2;
    }
    const int* offp = g_off + (size_t)slot * (N_NODES + 1);
    int e0 = offp[i] + csr_base(slot);
    int e1 = offp[i + 1] + csr_base(slot);
    for (int e = e0; e < e1; e++) {
        int s = g_csr_src[e];
        float nrm = g_csr_nrm[e];
        float4 v = *(const float4*)&g_x[(size_t)s * 256 + lane * 4];
        acc.x += nrm * v.x; acc.y += nrm * v.y;
        acc.z += nrm * v.z; acc.w += nrm * v.w;
        if (lane < 8) {
            float4 sv = *(const float4*)&fs[(size_t)s * 32 + lane * 4];
            accs.x += nrm * sv.x; accs.y += nrm * sv.y;
            accs.z += nrm * sv.z; accs.w += nrm * sv.w;
        }
    }
    float* ar = g_agg + (size_t)i * 288;
    *(float4*)(ar + lane * 4) = acc;
    if (lane < 8) *(float4*)(ar + 256 + lane * 4) = accs;
}

// ----------------------------- main GEMM (K=288, N=256, masked rows) -----------------

__global__ __launch_bounds__(256) void k_gemm288(const float* __restrict__ W,
                                                 const float* __restrict__ bias,
                                                 int layer, int topi) {
    int count = (layer >= 0) ? g_cnt[layer] : N_NODES;
    int base = blockIdx.x * 64;
    if (base >= count) return;
    float* out = topi ? g_pi : g_x;
    __shared__ float aT[32 * 68];
    __shared__ float Wt[32 * 256];
    __shared__ int rows[64];
    int t = threadIdx.x;
    if (t < 64) {
        int r = base + t;
        rows[t] = (r < count) ? ((layer >= 0) ? g_lists[layer * N_NODES + r] : r) : -1;
    }
    __syncthreads();
    int tr = t >> 4, tc = t & 15;
    float acc[4][16];
#pragma unroll
    for (int r = 0; r < 4; r++)
#pragma unroll
        for (int j = 0; j < 16; j++) acc[r][j] = 0.f;

    for (int k0 = 0; k0 < 288; k0 += 32) {
#pragma unroll
        for (int li = 0; li < 2; li++) {
            int idx = li * 256 + t;
            int r = idx >> 3;
            int k4 = idx & 7;
            int row = rows[r];
            float4 v;
            if (row >= 0) v = *(const float4*)&g_agg[(size_t)row * 288 + k0 + k4 * 4];
            else { v.x = v.y = v.z = v.w = 0.f; }
            aT[(k4 * 4 + 0) * 68 + r] = v.x;
            aT[(k4 * 4 + 1) * 68 + r] = v.y;
            aT[(k4 * 4 + 2) * 68 + r] = v.z;
            aT[(k4 * 4 + 3) * 68 + r] = v.w;
        }
#pragma unroll
        for (int li = 0; li < 8; li++) {
            int idx = li * 256 + t;
            int k = idx >> 6;
            int c4 = idx & 63;
            *(float4*)&Wt[k * 256 + c4 * 4] = *(const float4*)&W[(size_t)(k0 + k) * 256 + c4 * 4];
        }
        __syncthreads();
        for (int k = 0; k < 32; k++) {
            float4 a4 = *(const float4*)&aT[k * 68 + tr * 4];
            float a[4] = {a4.x, a4.y, a4.z, a4.w};
            float b[16];
            *(float4*)&b[0]  = *(const float4*)&Wt[k * 256 + tc * 16];
            *(float4*)&b[4]  = *(const float4*)&Wt[k * 256 + tc * 16 + 4];
            *(float4*)&b[8]  = *(const float4*)&Wt[k * 256 + tc * 16 + 8];
            *(float4*)&b[12] = *(const float4*)&Wt[k * 256 + tc * 16 + 12];
#pragma unroll
            for (int r = 0; r < 4; r++)
#pragma unroll
                for (int j = 0; j < 16; j++) acc[r][j] += a[r] * b[j];
        }
        __syncthreads();
    }
#pragma unroll
    for (int r = 0; r < 4; r++) {
        int row = rows[tr * 4 + r];
        if (row < 0) continue;
        float* op = out + (size_t)row * 256 + tc * 16;
#pragma unroll
        for (int j = 0; j < 16; j++) op[j] = acc[r][j] + bias[tc * 16 + j];
    }
}

// ----------------------------- misc -----------------------------

__global__ __launch_bounds__(256) void k_copy_rows(int layer) {
    int w = (blockIdx.x * blockDim.x + threadIdx.x) >> 6;
    int lane = threadIdx.x & 63;
    if (w >= g_cnt[layer]) return;
    int i = g_lists[layer * N_NODES + w];
    *(float4*)(g_x + (size_t)i * 256 + lane * 4) =
        *(const float4*)(g_pi + (size_t)i * 256 + lane * 4);
}

__global__ __launch_bounds__(256) void k_relu() {
    int i = blockIdx.x * blockDim.x + threadIdx.x;
    if (i >= N_NODES * 64) return;
    float4 v = ((float4*)g_x)[i];
    v.x = fmaxf(v.x, 0.f); v.y = fmaxf(v.y, 0.f);
    v.z = fmaxf(v.z, 0.f); v.w = fmaxf(v.w, 0.f);
    ((float4*)g_x)[i] = v;
}

__global__ __launch_bounds__(256) void k_pool(const int* __restrict__ batch) {
    __shared__ int bs[128];
    int i0 = blockIdx.x * 128;
    if (threadIdx.x < 128) {
        int i = i0 + threadIdx.x;
        bs[threadIdx.x] = (i < N_NODES) ? batch[i] : -1;
    }
    __syncthreads();
    int c = threadIdx.x;
    int lim = min(128, N_NODES - i0);
    float acc = 0.f;
    int cur = bs[0];
    for (int ii = 0; ii < lim; ii++) {
        int g = bs[ii];
        if (g != cur) { atomicAdd(&g_pooled[cur * 256 + c], acc); acc = 0.f; cur = g; }
        acc += g_x[(size_t)(i0 + ii) * 256 + c];
    }
    atomicAdd(&g_pooled[cur * 256 + c], acc);
}

__global__ void k_final(const float* __restrict__ W_lin, const float* __restrict__ b_lin,
                        float* __restrict__ out) {
    int g = blockIdx.x;
    int lane = threadIdx.x;  // 64
    float4 p = *(const float4*)(g_pooled + g * 256 + lane * 4);
    float4 w = *(const float4*)(W_lin + lane * 4);
    float s = p.x * w.x + p.y * w.y + p.z * w.z + p.w * w.w;
    for (int o = 32; o > 0; o >>= 1) s += __shfl_down(s, o);
    if (lane == 0) out[g] = s + b_lin[0];
}

// ----------------------------- host -----------------------------

extern "C" void kernel_launch(void* const* d_in, const int* in_sizes, int n_in,
                              void* d_out, int out_size, void* d_ws, size_t ws_size,
                              hipStream_t stream) {
    const float* xin   = (const float*)d_in[0];
    const float* fs    = (const float*)d_in[1];
    const int* ei      = (const int*)d_in[2];
    const int* inner   = (const int*)d_in[3];
    const int* fwd     = (const int*)d_in[4];
    const int* layers  = (const int*)d_in[6];
    const int* batch   = (const int*)d_in[7];
    const float* W_up  = (const float*)d_in[8];
    const float* b_up  = (const float*)d_in[9];
    const float* W_in  = (const float*)d_in[10];
    const float* b_in  = (const float*)d_in[11];
    const float* W_fw  = (const float*)d_in[12];
    const float* b_fw  = (const float*)d_in[13];
    const float* W_lin = (const float*)d_in[14];
    const float* b_lin = (const float*)d_in[15];
    float* out = (float*)d_out;

    // --- CSR build for the 9 live edge sets ---
    k_init<<<(NSETS * N_NODES + 255) / 256, 256, 0, stream>>>();
    k_count_all<<<(CSR_TOTAL + 255) / 256, 256, 0, stream>>>(ei, inner, fwd);
    k_dinv<<<(NSETS * N_NODES + 255) / 256, 256, 0, stream>>>();
    k_scan<<<NSETS, SCAN_T, 0, stream>>>();
    k_fill_all<<<(CSR_TOTAL + 255) / 256, 256, 0, stream>>>(ei, inner, fwd);
    k_lists<<<(N_NODES + 255) / 256, 256, 0, stream>>>(layers);

    // --- conv0 ---
    k_gather16<<<(N_NODES * 16 + 255) / 256, 256, 0, stream>>>(xin);
    k_gemm0<<<N_NODES / 8, 256, 0, stream>>>(W_up, b_up);

    auto conv = [&](int slot, const float* W, const float* bias, int layer, int topi) {
        k_gather<<<25000, 256, 0, stream>>>(fs, slot, layer);
        k_gemm288<<<(N_NODES + 63) / 64, 256, 0, stream>>>(W, bias, layer, topi);
    };

    for (int p = 0; p < NPROP; p++) {
        for (int il = 0; il < NLAYERS; il++) {
            if (il < NLAYERS - 1) {
                conv(1 + il, W_in, b_in, il, 0);
                conv(5 + il, W_fw, b_fw, il + 1, 0);   // fwd conv (il=3 fwd is dead)
            } else {
                conv(1 + il, W_in, b_in, -1, 1);       // full -> partial_inner
                k_copy_rows<<<25000, 256, 0, stream>>>(3);
            }
        }
        k_relu<<<(N_NODES * 64 + 255) / 256, 256, 0, stream>>>();
        for (int il = NLAYERS - 1; il >= 0; il--) {
            if (il >= 1) k_copy_rows<<<25000, 256, 0, stream>>>(il - 1);
            conv(1 + il, W_in, b_in, il, 0);
        }
        k_relu<<<(N_NODES * 64 + 255) / 256, 256, 0, stream>>>();
    }

    k_pool<<<(N_NODES + 127) / 128, 256, 0, stream>>>(batch);
    k_final<<<NGRAPHS, 64, 0, stream>>>(W_lin, b_lin, out);
}

// Round 6
// 2864.342 us; speedup vs baseline: 4.2239x; 1.3805x over previous
//
#include <hip/hip_runtime.h>

#define N_NODES 100000
#define NLAYERS 4
#define NPROP 2
#define NGRAPHS 50
#define NE_MAIN 400000
#define NE_SET 300000
#define NSETS 9            // 0=main, 1..4=inner, 5..8=fwd
#define CSR_TOTAL (NE_MAIN + 8 * NE_SET)

typedef __attribute__((ext_vector_type(8))) short bf8_t;  // 8 bf16 (4 VGPRs)
typedef __attribute__((ext_vector_type(4))) float f4_t;

// ---------------- static device scratch ----------------
__device__ __align__(16) float g_x[(size_t)N_NODES * 256];
__device__ __align__(16) float g_pi[(size_t)N_NODES * 256];
__device__ __align__(16) unsigned short g_aggh[(size_t)N_NODES * 288];
__device__ __align__(16) unsigned short g_aggl[(size_t)N_NODES * 288];
__device__ __align__(16) float g_agg16[(size_t)N_NODES * 16];
__device__ __align__(16) float g_dinv[NSETS * N_NODES];
__device__ __align__(16) float g_pooled[NGRAPHS * 256];
__device__ __align__(16) unsigned short g_WinhT[288 * 256];  // W_in^T hi [n][k]
__device__ __align__(16) unsigned short g_WinlT[288 * 256];
__device__ __align__(16) unsigned short g_WfwhT[288 * 256];
__device__ __align__(16) unsigned short g_WfwlT[288 * 256];
__device__ int g_deg[NSETS * N_NODES];
__device__ int g_cur[NSETS * N_NODES];
__device__ int g_off[NSETS * (N_NODES + 1)];
__device__ int g_csr_src[CSR_TOTAL];
__device__ float g_csr_nrm[CSR_TOTAL];
__device__ int g_cnt[4];
__device__ int g_lists[NLAYERS * N_NODES];

__host__ __device__ inline int csr_base(int slot) {
    return slot == 0 ? 0 : NE_MAIN + (slot - 1) * NE_SET;
}

__device__ inline unsigned short f2bf(float f) {  // RNE fp32 -> bf16
    unsigned u = __float_as_uint(f);
    return (unsigned short)((u + 0x7fffu + ((u >> 16) & 1u)) >> 16);
}
__device__ inline float bf2f(unsigned short b) {
    return __uint_as_float(((unsigned)b) << 16);
}

// decompose linear edge id over [main | inner0..3 | fwd0..3]
__device__ inline void edge_decode(int t, const int* ei, const int* inner, const int* fwd,
                                   int& slot, const int*& es, const int*& ed, int& e) {
    if (t < NE_MAIN) {
        slot = 0; e = t; es = ei; ed = ei + NE_MAIN;
    } else {
        int r = t - NE_MAIN;
        int grp = r / NE_SET;          // 0..7
        e = r - grp * NE_SET;
        slot = 1 + grp;                // 1..4 inner, 5..8 fwd
        const int* base = (grp < 4) ? (inner + grp * 2 * NE_SET)
                                    : (fwd + (grp - 4) * 2 * NE_SET);
        es = base; ed = base + NE_SET;
    }
}

// ----------------------------- setup -----------------------------

__global__ __launch_bounds__(256) void k_init() {
    int i = blockIdx.x * blockDim.x + threadIdx.x;
    if (i < NSETS * N_NODES) { g_deg[i] = 0; g_cur[i] = 0; }
    if (i < NGRAPHS * 256) g_pooled[i] = 0.f;
    if (i < 4) g_cnt[i] = 0;
}

__global__ __launch_bounds__(256) void k_count_all(const int* __restrict__ ei,
                                                   const int* __restrict__ inner,
                                                   const int* __restrict__ fwd) {
    int t = blockIdx.x * blockDim.x + threadIdx.x;
    if (t >= CSR_TOTAL) return;
    int slot, e; const int *es, *ed;
    edge_decode(t, ei, inner, fwd, slot, es, ed, e);
    atomicAdd(&g_deg[slot * N_NODES + ed[e]], 1);
}

__global__ __launch_bounds__(256) void k_dinv() {
    int i = blockIdx.x * blockDim.x + threadIdx.x;
    if (i < NSETS * N_NODES) g_dinv[i] = rsqrtf(1.0f + (float)g_deg[i]);
}

// split W into bf16 hi/lo, transposed to [n][k]; which: 0=W_in, 1=W_fw
// (globals resolved in device code — passing __device__ symbols from host is invalid)
__global__ __launch_bounds__(256) void k_wt(const float* __restrict__ W, int which) {
    int t = blockIdx.x * blockDim.x + threadIdx.x;  // over 288*256
    if (t >= 288 * 256) return;
    unsigned short* WhT = which ? g_WfwhT : g_WinhT;
    unsigned short* WlT = which ? g_WfwlT : g_WinlT;
    int k = t >> 8, n = t & 255;
    float w = W[t];
    unsigned short h = f2bf(w);
    unsigned short l = f2bf(w - bf2f(h));
    WhT[n * 288 + k] = h;
    WlT[n * 288 + k] = l;
}

#define SCAN_T 1024
#define SCAN_SEQ 8
__global__ __launch_bounds__(SCAN_T) void k_scan() {  // one block per set
    int set = blockIdx.x;
    const int* deg = g_deg + (size_t)set * N_NODES;
    int* off = g_off + (size_t)set * (N_NODES + 1);
    __shared__ int sm[SCAN_T];
    __shared__ int s_carry;
    int t = threadIdx.x;
    if (t == 0) s_carry = 0;
    __syncthreads();
    for (int base = 0; base < N_NODES; base += SCAN_T * SCAN_SEQ) {
        int v[SCAN_SEQ];
        int sum = 0;
        int idx0 = base + t * SCAN_SEQ;
#pragma unroll
        for (int j = 0; j < SCAN_SEQ; j++) {
            int id = idx0 + j;
            v[j] = (id < N_NODES) ? deg[id] : 0;
            sum += v[j];
        }
        sm[t] = sum;
        __syncthreads();
        for (int o = 1; o < SCAN_T; o <<= 1) {
            int u = (t >= o) ? sm[t - o] : 0;
            __syncthreads();
            sm[t] += u;
            __syncthreads();
        }
        int total = sm[SCAN_T - 1];
        int run = s_carry + sm[t] - sum;
#pragma unroll
        for (int j = 0; j < SCAN_SEQ; j++) {
            int id = idx0 + j;
            if (id < N_NODES) off[id] = run;
            run += v[j];
        }
        __syncthreads();
        if (t == 0) s_carry += total;
        __syncthreads();
    }
    if (t == 0) off[N_NODES] = s_carry;
}

__global__ __launch_bounds__(256) void k_fill_all(const int* __restrict__ ei,
                                                  const int* __restrict__ inner,
                                                  const int* __restrict__ fwd) {
    int t = blockIdx.x * blockDim.x + threadIdx.x;
    if (t >= CSR_TOTAL) return;
    int slot, e; const int *es, *ed;
    edge_decode(t, ei, inner, fwd, slot, es, ed, e);
    int s = es[e], d = ed[e];
    int pos = atomicAdd(&g_cur[slot * N_NODES + d], 1);
    int b = csr_base(slot) + g_off[slot * (N_NODES + 1) + d] + pos;
    g_csr_src[b] = s;
    g_csr_nrm[b] = g_dinv[slot * N_NODES + s] * g_dinv[slot * N_NODES + d];
}

// block-local histogram -> 4 global atomics per block
__global__ __launch_bounds__(256) void k_lists(const int* __restrict__ layers) {
    __shared__ int lcnt[4];
    __shared__ int lbase[4];
    int i = blockIdx.x * blockDim.x + threadIdx.x;
    if (threadIdx.x < 4) lcnt[threadIdx.x] = 0;
    __syncthreads();
    int l = -1, p = 0;
    if (i < N_NODES) {
        l = layers[i];
        p = atomicAdd(&lcnt[l], 1);
    }
    __syncthreads();
    if (threadIdx.x < 4) lbase[threadIdx.x] = atomicAdd(&g_cnt[threadIdx.x], lcnt[threadIdx.x]);
    __syncthreads();
    if (l >= 0) g_lists[l * N_NODES + lbase[l] + p] = i;
}

// ----------------------------- conv0 (K=16) -----------------------------

__global__ __launch_bounds__(256) void k_gather16(const float* __restrict__ xin) {
    int g = blockIdx.x * blockDim.x + threadIdx.x;
    int i = g >> 4, lane = g & 15;
    if (i >= N_NODES) return;
    float dv = g_dinv[i];
    float acc = dv * dv * xin[i * 16 + lane];
    int e0 = g_off[i], e1 = g_off[i + 1];
    for (int e = e0; e < e1; e++) {
        int s = g_csr_src[e];
        float nrm = g_csr_nrm[e];
        acc += nrm * xin[s * 16 + lane];
    }
    g_agg16[i * 16 + lane] = acc;
}

__global__ __launch_bounds__(256) void k_gemm0(const float* __restrict__ W,
                                               const float* __restrict__ bias) {
    __shared__ float a[128];
    int base = blockIdx.x * 8;
    int t = threadIdx.x;
    if (t < 128) a[t] = g_agg16[base * 16 + t];
    __syncthreads();
    float bb = bias[t];
    for (int r = 0; r < 8; r++) {
        float acc = bb;
#pragma unroll
        for (int k = 0; k < 16; k++) acc += a[r * 16 + k] * W[k * 256 + t];
        g_x[(size_t)(base + r) * 256 + t] = acc;
    }
}

// ------------- 288-dim gather (self-loop fused, writes bf16 hi/lo) -------------

__global__ __launch_bounds__(256) void k_gather(const float* __restrict__ fs,
                                                int slot, int layer) {
    int w = (blockIdx.x * blockDim.x + threadIdx.x) >> 6;
    int lane = threadIdx.x & 63;
    int count = (layer >= 0) ? g_cnt[layer] : N_NODES;
    if (w >= count) return;
    int i = (layer >= 0) ? g_lists[layer * N_NODES + w] : w;
    float dv = g_dinv[(size_t)slot * N_NODES + i];
    float d2 = dv * dv;
    float4 acc = *(const float4*)&g_x[(size_t)i * 256 + lane * 4];
    acc.x *= d2; acc.y *= d2; acc.z *= d2; acc.w *= d2;
    float4 accs = {0.f, 0.f, 0.f, 0.f};
    if (lane < 8) {
        accs = *(const float4*)&fs[(size_t)i * 32 + lane * 4];
        accs.x *= d2; accs.y *= d2; accs.z *= d2; accs.w *= d2;
    }
    const int* offp = g_off + (size_t)slot * (N_NODES + 1);
    int e0 = offp[i] + csr_base(slot);
    int e1 = offp[i + 1] + csr_base(slot);
    for (int e = e0; e < e1; e++) {
        int s = g_csr_src[e];
        float nrm = g_csr_nrm[e];
        float4 v = *(const float4*)&g_x[(size_t)s * 256 + lane * 4];
        acc.x += nrm * v.x; acc.y += nrm * v.y;
        acc.z += nrm * v.z; acc.w += nrm * v.w;
        if (lane < 8) {
            float4 sv = *(const float4*)&fs[(size_t)s * 32 + lane * 4];
            accs.x += nrm * sv.x; accs.y += nrm * sv.y;
            accs.z += nrm * sv.z; accs.w += nrm * sv.w;
        }
    }
    // split to bf16 hi/lo and store
    ushort4 h, l;
    h.x = f2bf(acc.x); l.x = f2bf(acc.x - bf2f(h.x));
    h.y = f2bf(acc.y); l.y = f2bf(acc.y - bf2f(h.y));
    h.z = f2bf(acc.z); l.z = f2bf(acc.z - bf2f(h.z));
    h.w = f2bf(acc.w); l.w = f2bf(acc.w - bf2f(h.w));
    *(ushort4*)&g_aggh[(size_t)i * 288 + lane * 4] = h;
    *(ushort4*)&g_aggl[(size_t)i * 288 + lane * 4] = l;
    if (lane < 8) {
        ushort4 hs, ls;
        hs.x = f2bf(accs.x); ls.x = f2bf(accs.x - bf2f(hs.x));
        hs.y = f2bf(accs.y); ls.y = f2bf(accs.y - bf2f(hs.y));
        hs.z = f2bf(accs.z); ls.z = f2bf(accs.z - bf2f(hs.z));
        hs.w = f2bf(accs.w); ls.w = f2bf(accs.w - bf2f(hs.w));
        *(ushort4*)&g_aggh[(size_t)i * 288 + 256 + lane * 4] = hs;
        *(ushort4*)&g_aggl[(size_t)i * 288 + 256 + lane * 4] = ls;
    }
}

// -------- main GEMM via MFMA bf16 3-term split (K=288, N=256, masked rows) --------
// block: 32 rows x 256 cols; wave: 32 rows x 64 cols (2 row-tiles x 4 col-tiles)
// which: 0 = W_in, 1 = W_fw (device-side global resolution)

__global__ __launch_bounds__(256) void k_gemm_mfma(int which,
                                                   const float* __restrict__ bias,
                                                   int layer, int topi) {
    int count = (layer >= 0) ? g_cnt[layer] : N_NODES;
    int base = blockIdx.x * 32;
    if (base >= count) return;
    const unsigned short* WhT = which ? g_WfwhT : g_WinhT;
    const unsigned short* WlT = which ? g_WfwlT : g_WinlT;
    float* out = topi ? g_pi : g_x;
    __shared__ int rows_s[32];
    int t = threadIdx.x;
    if (t < 32) {
        int r = base + t;
        rows_s[t] = (r < count) ? ((layer >= 0) ? g_lists[layer * N_NODES + r] : r) : -1;
    }
    __syncthreads();
    int wv = t >> 6;           // col stripe 0..3
    int lane = t & 63;
    int m = lane & 15, quad = lane >> 4;
    int n0 = wv * 64;
    int r0 = rows_s[m];
    int r1 = rows_s[16 + m];
    size_t a0 = (size_t)(r0 < 0 ? 0 : r0) * 288 + quad * 8;
    size_t a1 = (size_t)(r1 < 0 ? 0 : r1) * 288 + quad * 8;

    f4_t acc[2][4];
#pragma unroll
    for (int rt = 0; rt < 2; rt++)
#pragma unroll
        for (int ct = 0; ct < 4; ct++) acc[rt][ct] = (f4_t){0.f, 0.f, 0.f, 0.f};

    for (int k0 = 0; k0 < 288; k0 += 32) {
        bf8_t ah0 = *(const bf8_t*)&g_aggh[a0 + k0];
        bf8_t al0 = *(const bf8_t*)&g_aggl[a0 + k0];
        bf8_t ah1 = *(const bf8_t*)&g_aggh[a1 + k0];
        bf8_t al1 = *(const bf8_t*)&g_aggl[a1 + k0];
#pragma unroll
        for (int ct = 0; ct < 4; ct++) {
            int n = n0 + ct * 16 + m;
            bf8_t bh = *(const bf8_t*)&WhT[(size_t)n * 288 + k0 + quad * 8];
            bf8_t bl = *(const bf8_t*)&WlT[(size_t)n * 288 + k0 + quad * 8];
            acc[0][ct] = __builtin_amdgcn_mfma_f32_16x16x32_bf16(ah0, bh, acc[0][ct], 0, 0, 0);
            acc[0][ct] = __builtin_amdgcn_mfma_f32_16x16x32_bf16(al0, bh, acc[0][ct], 0, 0, 0);
            acc[0][ct] = __builtin_amdgcn_mfma_f32_16x16x32_bf16(ah0, bl, acc[0][ct], 0, 0, 0);
            acc[1][ct] = __builtin_amdgcn_mfma_f32_16x16x32_bf16(ah1, bh, acc[1][ct], 0, 0, 0);
            acc[1][ct] = __builtin_amdgcn_mfma_f32_16x16x32_bf16(al1, bh, acc[1][ct], 0, 0, 0);
            acc[1][ct] = __builtin_amdgcn_mfma_f32_16x16x32_bf16(ah1, bl, acc[1][ct], 0, 0, 0);
        }
    }
    // epilogue: C/D layout col=lane&15, row=quad*4+reg
#pragma unroll
    for (int rt = 0; rt < 2; rt++) {
#pragma unroll
        for (int r = 0; r < 4; r++) {
            int row = rows_s[rt * 16 + quad * 4 + r];
            if (row < 0) continue;
#pragma unroll
            for (int ct = 0; ct < 4; ct++) {
                int n = n0 + ct * 16 + m;
                out[(size_t)row * 256 + n] = acc[rt][ct][r] + bias[n];
            }
        }
    }
}

// ----------------------------- misc -----------------------------

__global__ __launch_bounds__(256) void k_copy_rows(int layer) {
    int w = (blockIdx.x * blockDim.x + threadIdx.x) >> 6;
    int lane = threadIdx.x & 63;
    if (w >= g_cnt[layer]) return;
    int i = g_lists[layer * N_NODES + w];
    *(float4*)(g_x + (size_t)i * 256 + lane * 4) =
        *(const float4*)(g_pi + (size_t)i * 256 + lane * 4);
}

__global__ __launch_bounds__(256) void k_relu() {
    int i = blockIdx.x * blockDim.x + threadIdx.x;
    if (i >= N_NODES * 64) return;
    float4 v = ((float4*)g_x)[i];
    v.x = fmaxf(v.x, 0.f); v.y = fmaxf(v.y, 0.f);
    v.z = fmaxf(v.z, 0.f); v.w = fmaxf(v.w, 0.f);
    ((float4*)g_x)[i] = v;
}

__global__ __launch_bounds__(256) void k_pool(const int* __restrict__ batch) {
    __shared__ int bs[128];
    int i0 = blockIdx.x * 128;
    if (threadIdx.x < 128) {
        int i = i0 + threadIdx.x;
        bs[threadIdx.x] = (i < N_NODES) ? batch[i] : -1;
    }
    __syncthreads();
    int c = threadIdx.x;
    int lim = min(128, N_NODES - i0);
    float acc = 0.f;
    int cur = bs[0];
    for (int ii = 0; ii < lim; ii++) {
        int g = bs[ii];
        if (g != cur) { atomicAdd(&g_pooled[cur * 256 + c], acc); acc = 0.f; cur = g; }
        acc += g_x[(size_t)(i0 + ii) * 256 + c];
    }
    atomicAdd(&g_pooled[cur * 256 + c], acc);
}

__global__ void k_final(const float* __restrict__ W_lin, const float* __restrict__ b_lin,
                        float* __restrict__ out) {
    int g = blockIdx.x;
    int lane = threadIdx.x;  // 64
    float4 p = *(const float4*)(g_pooled + g * 256 + lane * 4);
    float4 w = *(const float4*)(W_lin + lane * 4);
    float s = p.x * w.x + p.y * w.y + p.z * w.z + p.w * w.w;
    for (int o = 32; o > 0; o >>= 1) s += __shfl_down(s, o);
    if (lane == 0) out[g] = s + b_lin[0];
}

// ----------------------------- host -----------------------------

extern "C" void kernel_launch(void* const* d_in, const int* in_sizes, int n_in,
                              void* d_out, int out_size, void* d_ws, size_t ws_size,
                              hipStream_t stream) {
    const float* xin   = (const float*)d_in[0];
    const float* fs    = (const float*)d_in[1];
    const int* ei      = (const int*)d_in[2];
    const int* inner   = (const int*)d_in[3];
    const int* fwd     = (const int*)d_in[4];
    const int* layers  = (const int*)d_in[6];
    const int* batch   = (const int*)d_in[7];
    const float* W_up  = (const float*)d_in[8];
    const float* b_up  = (const float*)d_in[9];
    const float* W_in  = (const float*)d_in[10];
    const float* b_in  = (const float*)d_in[11];
    const float* W_fw  = (const float*)d_in[12];
    const float* b_fw  = (const float*)d_in[13];
    const float* W_lin = (const float*)d_in[14];
    const float* b_lin = (const float*)d_in[15];
    float* out = (float*)d_out;

    // --- CSR build + weight split ---
    k_init<<<(NSETS * N_NODES + 255) / 256, 256, 0, stream>>>();
    k_wt<<<(288 * 256 + 255) / 256, 256, 0, stream>>>(W_in, 0);
    k_wt<<<(288 * 256 + 255) / 256, 256, 0, stream>>>(W_fw, 1);
    k_count_all<<<(CSR_TOTAL + 255) / 256, 256, 0, stream>>>(ei, inner, fwd);
    k_dinv<<<(NSETS * N_NODES + 255) / 256, 256, 0, stream>>>();
    k_scan<<<NSETS, SCAN_T, 0, stream>>>();
    k_fill_all<<<(CSR_TOTAL + 255) / 256, 256, 0, stream>>>(ei, inner, fwd);
    k_lists<<<(N_NODES + 255) / 256, 256, 0, stream>>>(layers);

    // --- conv0 ---
    k_gather16<<<(N_NODES * 16 + 255) / 256, 256, 0, stream>>>(xin);
    k_gemm0<<<N_NODES / 8, 256, 0, stream>>>(W_up, b_up);

    auto conv = [&](int slot, int which, const float* bias, int layer, int topi) {
        k_gather<<<25000, 256, 0, stream>>>(fs, slot, layer);
        k_gemm_mfma<<<(N_NODES + 31) / 32, 256, 0, stream>>>(which, bias, layer, topi);
    };

    for (int p = 0; p < NPROP; p++) {
        for (int il = 0; il < NLAYERS; il++) {
            if (il < NLAYERS - 1) {
                conv(1 + il, 0, b_in, il, 0);
                conv(5 + il, 1, b_fw, il + 1, 0);   // il=3 fwd is dead
            } else {
                conv(1 + il, 0, b_in, -1, 1);       // full -> partial_inner
                k_copy_rows<<<25000, 256, 0, stream>>>(3);
            }
        }
        k_relu<<<(N_NODES * 64 + 255) / 256, 256, 0, stream>>>();
        for (int il = NLAYERS - 1; il >= 0; il--) {
            if (il >= 1) k_copy_rows<<<25000, 256, 0, stream>>>(il - 1);
            conv(1 + il, 0, b_in, il, 0);
        }
        k_relu<<<(N_NODES * 64 + 255) / 256, 256, 0, stream>>>();
    }

    k_pool<<<(N_NODES + 127) / 128, 256, 0, stream>>>(batch);
    k_final<<<NGRAPHS, 64, 0, stream>>>(W_lin, b_lin, out);
}

// Round 7
// 2281.594 us; speedup vs baseline: 5.3027x; 1.2554x over previous
//
#include <hip/hip_runtime.h>

#define N_NODES 100000
#define NLAYERS 4
#define NPROP 2
#define NGRAPHS 50
#define NE_MAIN 400000
#define NE_SET 300000
#define NSETS 9            // 0=main, 1..4=inner, 5..8=fwd
#define CSR_TOTAL (NE_MAIN + 8 * NE_SET)
#define ASTR 296           // LDS agg row stride (shorts): 148 dwords -> 2-way banks on b128

typedef __attribute__((ext_vector_type(8))) short bf8_t;  // 8 bf16 (4 VGPRs)
typedef __attribute__((ext_vector_type(4))) float f4_t;

// ---------------- static device scratch ----------------
__device__ __align__(16) float g_x[(size_t)N_NODES * 256];
__device__ __align__(16) float g_pi[(size_t)N_NODES * 256];
__device__ __align__(16) float g_agg16[(size_t)N_NODES * 16];
__device__ __align__(16) float g_dinv[NSETS * N_NODES];
__device__ __align__(16) float g_pooled[NGRAPHS * 256];
__device__ __align__(16) unsigned short g_WinhT[288 * 256];  // W_in^T hi [n][k]
__device__ __align__(16) unsigned short g_WinlT[288 * 256];
__device__ __align__(16) unsigned short g_WfwhT[288 * 256];
__device__ __align__(16) unsigned short g_WfwlT[288 * 256];
__device__ int g_deg[NSETS * N_NODES];
__device__ int g_cur[NSETS * N_NODES];
__device__ int g_off[NSETS * (N_NODES + 1)];
__device__ __align__(8) int2 g_csr[CSR_TOTAL];   // {src, float_bits(nrm)}
__device__ int g_cnt[4];
__device__ int g_lists[NLAYERS * N_NODES];

__host__ __device__ inline int csr_base(int slot) {
    return slot == 0 ? 0 : NE_MAIN + (slot - 1) * NE_SET;
}

__device__ inline unsigned short f2bf(float f) {  // RNE fp32 -> bf16
    unsigned u = __float_as_uint(f);
    return (unsigned short)((u + 0x7fffu + ((u >> 16) & 1u)) >> 16);
}
__device__ inline float bf2f(unsigned short b) {
    return __uint_as_float(((unsigned)b) << 16);
}

// decompose linear edge id over [main | inner0..3 | fwd0..3]
__device__ inline void edge_decode(int t, const int* ei, const int* inner, const int* fwd,
                                   int& slot, const int*& es, const int*& ed, int& e) {
    if (t < NE_MAIN) {
        slot = 0; e = t; es = ei; ed = ei + NE_MAIN;
    } else {
        int r = t - NE_MAIN;
        int grp = r / NE_SET;          // 0..7
        e = r - grp * NE_SET;
        slot = 1 + grp;                // 1..4 inner, 5..8 fwd
        const int* base = (grp < 4) ? (inner + grp * 2 * NE_SET)
                                    : (fwd + (grp - 4) * 2 * NE_SET);
        es = base; ed = base + NE_SET;
    }
}

// ----------------------------- setup -----------------------------

__global__ __launch_bounds__(256) void k_init() {
    int i = blockIdx.x * blockDim.x + threadIdx.x;
    if (i < NSETS * N_NODES) g_deg[i] = 0;
    if (i < NGRAPHS * 256) g_pooled[i] = 0.f;
    if (i < 4) g_cnt[i] = 0;
}

__global__ __launch_bounds__(256) void k_count_all(const int* __restrict__ ei,
                                                   const int* __restrict__ inner,
                                                   const int* __restrict__ fwd) {
    int t = blockIdx.x * blockDim.x + threadIdx.x;
    if (t >= CSR_TOTAL) return;
    int slot, e; const int *es, *ed;
    edge_decode(t, ei, inner, fwd, slot, es, ed, e);
    atomicAdd(&g_deg[slot * N_NODES + ed[e]], 1);
}

__global__ __launch_bounds__(256) void k_dinv() {
    int i = blockIdx.x * blockDim.x + threadIdx.x;
    if (i < NSETS * N_NODES) g_dinv[i] = rsqrtf(1.0f + (float)g_deg[i]);
}

// split W into bf16 hi/lo, transposed to [n][k]; which: 0=W_in, 1=W_fw
__global__ __launch_bounds__(256) void k_wt(const float* __restrict__ W, int which) {
    int t = blockIdx.x * blockDim.x + threadIdx.x;  // over 288*256
    if (t >= 288 * 256) return;
    unsigned short* WhT = which ? g_WfwhT : g_WinhT;
    unsigned short* WlT = which ? g_WfwlT : g_WinlT;
    int k = t >> 8, n = t & 255;
    float w = W[t];
    unsigned short h = f2bf(w);
    unsigned short l = f2bf(w - bf2f(h));
    WhT[n * 288 + k] = h;
    WlT[n * 288 + k] = l;
}

#define SCAN_T 1024
#define SCAN_SEQ 8
__global__ __launch_bounds__(SCAN_T) void k_scan() {  // one block per set; also seeds g_cur=off
    int set = blockIdx.x;
    const int* deg = g_deg + (size_t)set * N_NODES;
    int* off = g_off + (size_t)set * (N_NODES + 1);
    int* cur = g_cur + (size_t)set * N_NODES;
    __shared__ int sm[SCAN_T];
    __shared__ int s_carry;
    int t = threadIdx.x;
    if (t == 0) s_carry = 0;
    __syncthreads();
    for (int base = 0; base < N_NODES; base += SCAN_T * SCAN_SEQ) {
        int v[SCAN_SEQ];
        int sum = 0;
        int idx0 = base + t * SCAN_SEQ;
#pragma unroll
        for (int j = 0; j < SCAN_SEQ; j++) {
            int id = idx0 + j;
            v[j] = (id < N_NODES) ? deg[id] : 0;
            sum += v[j];
        }
        sm[t] = sum;
        __syncthreads();
        for (int o = 1; o < SCAN_T; o <<= 1) {
            int u = (t >= o) ? sm[t - o] : 0;
            __syncthreads();
            sm[t] += u;
            __syncthreads();
        }
        int total = sm[SCAN_T - 1];
        int run = s_carry + sm[t] - sum;
#pragma unroll
        for (int j = 0; j < SCAN_SEQ; j++) {
            int id = idx0 + j;
            if (id < N_NODES) { off[id] = run; cur[id] = run; }
            run += v[j];
        }
        __syncthreads();
        if (t == 0) s_carry += total;
        __syncthreads();
    }
    if (t == 0) off[N_NODES] = s_carry;
}

__global__ __launch_bounds__(256) void k_fill_all(const int* __restrict__ ei,
                                                  const int* __restrict__ inner,
                                                  const int* __restrict__ fwd) {
    int t = blockIdx.x * blockDim.x + threadIdx.x;
    if (t >= CSR_TOTAL) return;
    int slot, e; const int *es, *ed;
    edge_decode(t, ei, inner, fwd, slot, es, ed, e);
    int s = es[e], d = ed[e];
    int pos = atomicAdd(&g_cur[slot * N_NODES + d], 1);   // absolute slot (cur seeded = off)
    float nrm = g_dinv[slot * N_NODES + s] * g_dinv[slot * N_NODES + d];
    g_csr[csr_base(slot) + pos] = make_int2(s, __float_as_int(nrm));
}

// block-local histogram -> 4 global atomics per block
__global__ __launch_bounds__(256) void k_lists(const int* __restrict__ layers) {
    __shared__ int lcnt[4];
    __shared__ int lbase[4];
    int i = blockIdx.x * blockDim.x + threadIdx.x;
    if (threadIdx.x < 4) lcnt[threadIdx.x] = 0;
    __syncthreads();
    int l = -1, p = 0;
    if (i < N_NODES) {
        l = layers[i];
        p = atomicAdd(&lcnt[l], 1);
    }
    __syncthreads();
    if (threadIdx.x < 4) lbase[threadIdx.x] = atomicAdd(&g_cnt[threadIdx.x], lcnt[threadIdx.x]);
    __syncthreads();
    if (l >= 0) g_lists[l * N_NODES + lbase[l] + p] = i;
}

// ----------------------------- conv0 (K=16) -----------------------------

__global__ __launch_bounds__(256) void k_gather16(const float* __restrict__ xin) {
    int g = blockIdx.x * blockDim.x + threadIdx.x;
    int i = g >> 4, lane = g & 15;
    if (i >= N_NODES) return;
    float dv = g_dinv[i];
    float acc = dv * dv * xin[i * 16 + lane];
    int e0 = g_off[i], e1 = g_off[i + 1];
    for (int e = e0; e < e1; e++) {
        int2 sn = g_csr[e];
        acc += __int_as_float(sn.y) * xin[sn.x * 16 + lane];
    }
    g_agg16[i * 16 + lane] = acc;
}

__global__ __launch_bounds__(256) void k_gemm0(const float* __restrict__ W,
                                               const float* __restrict__ bias) {
    __shared__ float a[128];
    int base = blockIdx.x * 8;
    int t = threadIdx.x;
    if (t < 128) a[t] = g_agg16[base * 16 + t];
    __syncthreads();
    float bb = bias[t];
    for (int r = 0; r < 8; r++) {
        float acc = bb;
#pragma unroll
        for (int k = 0; k < 16; k++) acc += a[r * 16 + k] * W[k * 256 + t];
        g_x[(size_t)(base + r) * 256 + t] = acc;
    }
}

// -------- fused conv: CSR gather -> LDS (bf16 hi/lo) -> 3-term MFMA GEMM --------
// block: 32 rows x 256 cols, 4 waves. Phase 1: wave w gathers rows w*8..w*8+7.
// Phase 2: wave w computes col stripe w*64..w*64+63.

__global__ __launch_bounds__(256) void k_conv(const float* __restrict__ fs,
                                              int slot, int which,
                                              const float* __restrict__ bias,
                                              int layer, int topi) {
    int count = (layer >= 0) ? g_cnt[layer] : N_NODES;
    int base = blockIdx.x * 32;
    if (base >= count) return;
    const unsigned short* WhT = which ? g_WfwhT : g_WinhT;
    const unsigned short* WlT = which ? g_WfwlT : g_WinlT;
    float* out = topi ? g_pi : g_x;

    __shared__ unsigned short lds_h[32 * ASTR];
    __shared__ unsigned short lds_l[32 * ASTR];
    __shared__ int rows_s[32];
    int t = threadIdx.x;
    if (t < 32) {
        int r = base + t;
        rows_s[t] = (r < count) ? ((layer >= 0) ? g_lists[layer * N_NODES + r] : r) : -1;
    }
    __syncthreads();

    int wv = t >> 6, lane = t & 63;

    // ---- phase 1: gather 8 rows per wave into LDS ----
    const int* offp = g_off + (size_t)slot * (N_NODES + 1);
    int cb = csr_base(slot);
    for (int rr = 0; rr < 8; rr++) {
        int lr = wv * 8 + rr;
        int row = rows_s[lr];
        float4 acc = {0.f, 0.f, 0.f, 0.f};
        float4 accs = {0.f, 0.f, 0.f, 0.f};
        if (row >= 0) {
            float dv = g_dinv[(size_t)slot * N_NODES + row];
            float d2 = dv * dv;
            acc = *(const float4*)&g_x[(size_t)row * 256 + lane * 4];
            acc.x *= d2; acc.y *= d2; acc.z *= d2; acc.w *= d2;
            if (lane < 8) {
                accs = *(const float4*)&fs[(size_t)row * 32 + lane * 4];
                accs.x *= d2; accs.y *= d2; accs.z *= d2; accs.w *= d2;
            }
            int e0 = offp[row] + cb, e1 = offp[row + 1] + cb;
            for (int e = e0; e < e1; e++) {
                int2 sn = g_csr[e];
                int s = sn.x;
                float nrm = __int_as_float(sn.y);
                float4 v = *(const float4*)&g_x[(size_t)s * 256 + lane * 4];
                acc.x += nrm * v.x; acc.y += nrm * v.y;
                acc.z += nrm * v.z; acc.w += nrm * v.w;
                if (lane < 8) {
                    float4 sv = *(const float4*)&fs[(size_t)s * 32 + lane * 4];
                    accs.x += nrm * sv.x; accs.y += nrm * sv.y;
                    accs.z += nrm * sv.z; accs.w += nrm * sv.w;
                }
            }
        }
        ushort4 h, l;
        h.x = f2bf(acc.x); l.x = f2bf(acc.x - bf2f(h.x));
        h.y = f2bf(acc.y); l.y = f2bf(acc.y - bf2f(h.y));
        h.z = f2bf(acc.z); l.z = f2bf(acc.z - bf2f(h.z));
        h.w = f2bf(acc.w); l.w = f2bf(acc.w - bf2f(h.w));
        *(ushort4*)&lds_h[lr * ASTR + lane * 4] = h;
        *(ushort4*)&lds_l[lr * ASTR + lane * 4] = l;
        if (lane < 8) {
            ushort4 hs, ls;
            hs.x = f2bf(accs.x); ls.x = f2bf(accs.x - bf2f(hs.x));
            hs.y = f2bf(accs.y); ls.y = f2bf(accs.y - bf2f(hs.y));
            hs.z = f2bf(accs.z); ls.z = f2bf(accs.z - bf2f(hs.z));
            hs.w = f2bf(accs.w); ls.w = f2bf(accs.w - bf2f(hs.w));
            *(ushort4*)&lds_h[lr * ASTR + 256 + lane * 4] = hs;
            *(ushort4*)&lds_l[lr * ASTR + 256 + lane * 4] = ls;
        }
    }
    __syncthreads();

    // ---- phase 2: MFMA ----
    int m = lane & 15, quad = lane >> 4;
    int n0 = wv * 64;
    f4_t acc2[2][4];
#pragma unroll
    for (int rt = 0; rt < 2; rt++)
#pragma unroll
        for (int ct = 0; ct < 4; ct++) acc2[rt][ct] = (f4_t){0.f, 0.f, 0.f, 0.f};

    for (int k0 = 0; k0 < 288; k0 += 32) {
        bf8_t ah0 = *(const bf8_t*)&lds_h[m * ASTR + k0 + quad * 8];
        bf8_t al0 = *(const bf8_t*)&lds_l[m * ASTR + k0 + quad * 8];
        bf8_t ah1 = *(const bf8_t*)&lds_h[(16 + m) * ASTR + k0 + quad * 8];
        bf8_t al1 = *(const bf8_t*)&lds_l[(16 + m) * ASTR + k0 + quad * 8];
#pragma unroll
        for (int ct = 0; ct < 4; ct++) {
            int n = n0 + ct * 16 + m;
            bf8_t bh = *(const bf8_t*)&WhT[(size_t)n * 288 + k0 + quad * 8];
            bf8_t bl = *(const bf8_t*)&WlT[(size_t)n * 288 + k0 + quad * 8];
            acc2[0][ct] = __builtin_amdgcn_mfma_f32_16x16x32_bf16(ah0, bh, acc2[0][ct], 0, 0, 0);
            acc2[0][ct] = __builtin_amdgcn_mfma_f32_16x16x32_bf16(al0, bh, acc2[0][ct], 0, 0, 0);
            acc2[0][ct] = __builtin_amdgcn_mfma_f32_16x16x32_bf16(ah0, bl, acc2[0][ct], 0, 0, 0);
            acc2[1][ct] = __builtin_amdgcn_mfma_f32_16x16x32_bf16(ah1, bh, acc2[1][ct], 0, 0, 0);
            acc2[1][ct] = __builtin_amdgcn_mfma_f32_16x16x32_bf16(al1, bh, acc2[1][ct], 0, 0, 0);
            acc2[1][ct] = __builtin_amdgcn_mfma_f32_16x16x32_bf16(ah1, bl, acc2[1][ct], 0, 0, 0);
        }
    }
    // epilogue: C/D layout col=lane&15, row=quad*4+reg
#pragma unroll
    for (int rt = 0; rt < 2; rt++) {
#pragma unroll
        for (int r = 0; r < 4; r++) {
            int row = rows_s[rt * 16 + quad * 4 + r];
            if (row < 0) continue;
#pragma unroll
            for (int ct = 0; ct < 4; ct++) {
                int n = n0 + ct * 16 + m;
                out[(size_t)row * 256 + n] = acc2[rt][ct][r] + bias[n];
            }
        }
    }
}

// ----------------------------- misc -----------------------------

__global__ __launch_bounds__(256) void k_copy_rows(int layer) {
    int w = (blockIdx.x * blockDim.x + threadIdx.x) >> 6;
    int lane = threadIdx.x & 63;
    if (w >= g_cnt[layer]) return;
    int i = g_lists[layer * N_NODES + w];
    *(float4*)(g_x + (size_t)i * 256 + lane * 4) =
        *(const float4*)(g_pi + (size_t)i * 256 + lane * 4);
}

__global__ __launch_bounds__(256) void k_relu() {
    int i = blockIdx.x * blockDim.x + threadIdx.x;
    if (i >= N_NODES * 64) return;
    float4 v = ((float4*)g_x)[i];
    v.x = fmaxf(v.x, 0.f); v.y = fmaxf(v.y, 0.f);
    v.z = fmaxf(v.z, 0.f); v.w = fmaxf(v.w, 0.f);
    ((float4*)g_x)[i] = v;
}

__global__ __launch_bounds__(256) void k_pool(const int* __restrict__ batch) {
    __shared__ int bs[128];
    int i0 = blockIdx.x * 128;
    if (threadIdx.x < 128) {
        int i = i0 + threadIdx.x;
        bs[threadIdx.x] = (i < N_NODES) ? batch[i] : -1;
    }
    __syncthreads();
    int c = threadIdx.x;
    int lim = min(128, N_NODES - i0);
    float acc = 0.f;
    int cur = bs[0];
    for (int ii = 0; ii < lim; ii++) {
        int g = bs[ii];
        if (g != cur) { atomicAdd(&g_pooled[cur * 256 + c], acc); acc = 0.f; cur = g; }
        acc += g_x[(size_t)(i0 + ii) * 256 + c];
    }
    atomicAdd(&g_pooled[cur * 256 + c], acc);
}

__global__ void k_final(const float* __restrict__ W_lin, const float* __restrict__ b_lin,
                        float* __restrict__ out) {
    int g = blockIdx.x;
    int lane = threadIdx.x;  // 64
    float4 p = *(const float4*)(g_pooled + g * 256 + lane * 4);
    float4 w = *(const float4*)(W_lin + lane * 4);
    float s = p.x * w.x + p.y * w.y + p.z * w.z + p.w * w.w;
    for (int o = 32; o > 0; o >>= 1) s += __shfl_down(s, o);
    if (lane == 0) out[g] = s + b_lin[0];
}

// ----------------------------- host -----------------------------

extern "C" void kernel_launch(void* const* d_in, const int* in_sizes, int n_in,
                              void* d_out, int out_size, void* d_ws, size_t ws_size,
                              hipStream_t stream) {
    const float* xin   = (const float*)d_in[0];
    const float* fs    = (const float*)d_in[1];
    const int* ei      = (const int*)d_in[2];
    const int* inner   = (const int*)d_in[3];
    const int* fwd     = (const int*)d_in[4];
    const int* layers  = (const int*)d_in[6];
    const int* batch   = (const int*)d_in[7];
    const float* W_up  = (const float*)d_in[8];
    const float* b_up  = (const float*)d_in[9];
    const float* W_in  = (const float*)d_in[10];
    const float* b_in  = (const float*)d_in[11];
    const float* W_fw  = (const float*)d_in[12];
    const float* b_fw  = (const float*)d_in[13];
    const float* W_lin = (const float*)d_in[14];
    const float* b_lin = (const float*)d_in[15];
    float* out = (float*)d_out;

    // --- CSR build + weight split ---
    k_init<<<(NSETS * N_NODES + 255) / 256, 256, 0, stream>>>();
    k_wt<<<(288 * 256 + 255) / 256, 256, 0, stream>>>(W_in, 0);
    k_wt<<<(288 * 256 + 255) / 256, 256, 0, stream>>>(W_fw, 1);
    k_count_all<<<(CSR_TOTAL + 255) / 256, 256, 0, stream>>>(ei, inner, fwd);
    k_dinv<<<(NSETS * N_NODES + 255) / 256, 256, 0, stream>>>();
    k_scan<<<NSETS, SCAN_T, 0, stream>>>();
    k_fill_all<<<(CSR_TOTAL + 255) / 256, 256, 0, stream>>>(ei, inner, fwd);
    k_lists<<<(N_NODES + 255) / 256, 256, 0, stream>>>(layers);

    // --- conv0 ---
    k_gather16<<<(N_NODES * 16 + 255) / 256, 256, 0, stream>>>(xin);
    k_gemm0<<<N_NODES / 8, 256, 0, stream>>>(W_up, b_up);

    auto conv = [&](int slot, int which, const float* bias, int layer, int topi) {
        k_conv<<<(N_NODES + 31) / 32, 256, 0, stream>>>(fs, slot, which, bias, layer, topi);
    };

    for (int p = 0; p < NPROP; p++) {
        for (int il = 0; il < NLAYERS; il++) {
            if (il < NLAYERS - 1) {
                conv(1 + il, 0, b_in, il, 0);
                conv(5 + il, 1, b_fw, il + 1, 0);   // il=3 fwd is dead
            } else {
                conv(1 + il, 0, b_in, -1, 1);       // full -> partial_inner
                k_copy_rows<<<25000, 256, 0, stream>>>(3);
            }
        }
        k_relu<<<(N_NODES * 64 + 255) / 256, 256, 0, stream>>>();
        for (int il = NLAYERS - 1; il >= 0; il--) {
            if (il >= 1) k_copy_rows<<<25000, 256, 0, stream>>>(il - 1);
            conv(1 + il, 0, b_in, il, 0);
        }
        k_relu<<<(N_NODES * 64 + 255) / 256, 256, 0, stream>>>();
    }

    k_pool<<<(N_NODES + 127) / 128, 256, 0, stream>>>(batch);
    k_final<<<NGRAPHS, 64, 0, stream>>>(W_lin, b_lin, out);
}